// Round 16
// baseline (71.338 us; speedup 1.0000x reference)
//
#include <hip/hip_runtime.h>

// Problem constants
#define NQ 20
#define DIMQ (1 << NQ)          // 2^20
#define NB 16                   // BATCH
#define NT 4                    // N_TERMS
#define RBITS 15                // low bits untouched by gates
#define NCOL (1 << (RBITS + 4)) // 2^15 r-values * 16 batches = 524288 columns

// U table layout (ws + LDS): [k][ij][bp][4] with slots {re_b0, re_b1, im_b0, im_b1}
//   float4 index = (k*16 + ij)*8 + bp ;  b0 = 2*bp, b1 = 2*bp+1.
//   4*16*8*4 = 2048 floats = 8 KiB. LDS reads: 8 distinct float4 addrs/wave,
//   stride 16 B -> 32 banks covered, 8-lane broadcast each: conflict-free.
#define UTOT 2048

// native 2-float vector for nontemporal builtins (HIP float2 is a class type)
typedef float v2f __attribute__((ext_vector_type(2)));

// DPP quad_perm lane swaps (pure VALU, in-quad): ^1 = 0xB1, ^2 = 0x4E, ^3 = 0x1B.
template <int PAT>
__device__ __forceinline__ float2 dpp2(float2 x) {
  float2 r;
  r.x = __builtin_bit_cast(float, __builtin_amdgcn_mov_dpp(
            __builtin_bit_cast(int, x.x), PAT, 0xF, 0xF, true));
  r.y = __builtin_bit_cast(float, __builtin_amdgcn_mov_dpp(
            __builtin_bit_cast(int, x.y), PAT, 0xF, 0xF, true));
  return r;
}

// Packed complex MAC over a column-pair: (o_r,o_i) += (u_r,u_i)*(s_r,s_i)
// componentwise in each half (col0 in lo, col1 in hi). 4 pk-FMAs = 2 cMACs.
__device__ __forceinline__ void pk_cfma(float2& o_r, float2& o_i,
                                        const float2 u_r, const float2 u_i,
                                        const float2 s_r, const float2 s_i) {
  asm("v_pk_fma_f32 %0, %2, %4, %0\n\t"
      "v_pk_fma_f32 %0, %3, %5, %0 neg_lo:[1,0,0] neg_hi:[1,0,0]\n\t"
      "v_pk_fma_f32 %1, %2, %5, %1\n\t"
      "v_pk_fma_f32 %1, %3, %4, %1"
      : "+v"(o_r), "+v"(o_i)
      : "v"(u_r), "v"(u_i), "v"(s_r), "v"(s_i));
}

// ---------------------------------------------------------------------------
// Kernel A: U[k,b] = exp(-i * H_k * t_{k,b}),  H_k = 0.5*(A + A^H), A = Hr + i Hi
// 256 threads: 64 tasks (k,b) x 4 rows. Scaling (2^-4) + 8-term Taylor +
// 4 squarings (trunc error ~1e-10, invisible at fp32 / 2.1e-4 threshold).
// ---------------------------------------------------------------------------
__global__ __launch_bounds__(256) void compute_u_kernel(
    const float* __restrict__ Hre, const float* __restrict__ Him,
    const float* __restrict__ tevo, float* __restrict__ uout) {
  __shared__ float er_s[64][4][4];
  __shared__ float ei_s[64][4][4];

  const int tid  = threadIdx.x;   // 0..255
  const int task = tid >> 2;      // 0..63
  const int row  = tid & 3;       // 0..3
  const int k    = task >> 4;     // 0..3
  const int b    = task & 15;     // 0..15

  float Ar[4][4], Ai[4][4];
#pragma unroll
  for (int i = 0; i < 4; i++) {
#pragma unroll
    for (int j = 0; j < 4; j++) {
      Ar[i][j] = Hre[k * 16 + i * 4 + j];
      Ai[i][j] = Him[k * 16 + i * 4 + j];
    }
  }
  const float t = tevo[k * NB + b];
  const float ts = t * (1.0f / 16.0f);  // scale 2^-4 folded in

  // G = -i * H * ts ; H = 0.5*(A + A^H)
  float Gr[4][4], Gi[4][4];
#pragma unroll
  for (int i = 0; i < 4; i++) {
#pragma unroll
    for (int j = 0; j < 4; j++) {
      const float hr = 0.5f * (Ar[i][j] + Ar[j][i]);
      const float hi = 0.5f * (Ai[i][j] - Ai[j][i]);
      Gr[i][j] = ts * hi;
      Gi[i][j] = -ts * hr;
    }
  }

  // Taylor: E = I + sum_{m=1..8} G^m/m!   (row `row` only; full G in regs)
  float Er[4], Ei[4], Tr[4], Ti[4];
#pragma unroll
  for (int j = 0; j < 4; j++) {
    Er[j] = (j == row) ? 1.0f : 0.0f;
    Ei[j] = 0.0f;
    Tr[j] = Er[j];
    Ti[j] = 0.0f;
  }
#pragma unroll
  for (int m = 1; m <= 8; m++) {
    const float inv = 1.0f / (float)m;
    float nr[4], ni[4];
#pragma unroll
    for (int j = 0; j < 4; j++) {
      float ar = 0.0f, ai = 0.0f;
#pragma unroll
      for (int p = 0; p < 4; p++) {
        ar += Tr[p] * Gr[p][j] - Ti[p] * Gi[p][j];
        ai += Tr[p] * Gi[p][j] + Ti[p] * Gr[p][j];
      }
      nr[j] = ar * inv;
      ni[j] = ai * inv;
    }
#pragma unroll
    for (int j = 0; j < 4; j++) {
      Tr[j] = nr[j]; Ti[j] = ni[j];
      Er[j] += nr[j]; Ei[j] += ni[j];
    }
  }

  // 4 squarings via LDS (uniform trip count -> barriers are safe)
  for (int q = 0; q < 4; q++) {
    __syncthreads();
#pragma unroll
    for (int j = 0; j < 4; j++) {
      er_s[task][row][j] = Er[j];
      ei_s[task][row][j] = Ei[j];
    }
    __syncthreads();
    float nr[4], ni[4];
#pragma unroll
    for (int j = 0; j < 4; j++) {
      float ar = 0.0f, ai = 0.0f;
#pragma unroll
      for (int p = 0; p < 4; p++) {
        ar += Er[p] * er_s[task][p][j] - Ei[p] * ei_s[task][p][j];
        ai += Er[p] * ei_s[task][p][j] + Ei[p] * er_s[task][p][j];
      }
      nr[j] = ar; ni[j] = ai;
    }
#pragma unroll
    for (int j = 0; j < 4; j++) { Er[j] = nr[j]; Ei[j] = ni[j]; }
  }

  // Store U: layout [k][ij][bp][re_b0, re_b1, im_b0, im_b1]
  const int bp = b >> 1;
  const int sl = b & 1;
#pragma unroll
  for (int j = 0; j < 4; j++) {
    const int ij = row * 4 + j;
    uout[((k * 16 + ij) * 8 + bp) * 4 + sl]     = Er[j];
    uout[((k * 16 + ij) * 8 + bp) * 4 + 2 + sl] = Ei[j];
  }
}

// ---------------------------------------------------------------------------
// Kernel B (col-pair + quad partition, fully packed):
// Each QUAD of lanes owns a column-PAIR (adjacent cols -> 8B float2 accesses,
// the coalescing sweet spot); lane q = tid&3 owns g-quadrant q (8 g x 2 cols).
//   p = tid>>2 (col-pair 0..63), col2 = blockIdx*128 + 2p, bp = p&7.
// Coalescing: per load/store instr, each q-group is 16 lanes x 8B = one full
// 128B line (4 lines/instr) -- no amplification (fixes r12).
//   k=3 (g[1:0]), k=2 (g[2:1]): in-thread.
//   k=1 (g[3:2]): bit3 = q&1 -> partner lane^1 via DPP.
//   k=0 (g[4:3] = q): rotations d=1..3 via DPP 0xB1/0x4E/0x1B.
// All complex MACs are packed over the col-pair (u packed as (u_b0,u_b1)).
// Per-wave U staging (8 KiB, no barrier; waves drift freely); 32 KiB/block
// -> 5 blocks/CU. U LDS reads conflict-free broadcast.
// ---------------------------------------------------------------------------
__global__ __launch_bounds__(256, 4) void apply_gates_kernel(
    const float* __restrict__ sre, const float* __restrict__ sim,
    const float* __restrict__ u, float* __restrict__ out) {
  __shared__ __align__(16) float ul[4 * UTOT];      // 32 KiB: one region/wave
  const int tid  = threadIdx.x;
  const int p    = tid >> 2;                        // col-pair index 0..63
  const int q    = tid & 3;                         // owned g-quadrant
  const int q0   = q & 1;                           // g bit 3
  const int col2 = blockIdx.x * 128 + 2 * p;        // even column
  const int bp   = p & 7;                           // b-pair index

  // (1) own 8 g x col-pair: 16 x 8B loads, issued first
  float2 sr[8], si[8];
#pragma unroll
  for (int m = 0; m < 8; m++) {
    const int off = col2 + ((q * 8 + m) << 19);
    sr[m] = *(const float2*)(sre + off);
    si[m] = *(const float2*)(sim + off);
  }

  // (2) per-wave U staging: 2048 floats = 512 float4; 8 float4 per lane
  const int w = tid >> 6;
  const int l = tid & 63;
  float* uw = ul + w * UTOT;
  {
    const float4* u4 = (const float4*)u;
    float4* ul4 = (float4*)uw;
#pragma unroll
    for (int t = 0; t < 8; t++) ul4[l + 64 * t] = u4[l + 64 * t];
  }
  // no barrier: this wave only reads the region it just wrote (lgkmcnt).

  // entry accessor: float4 {re0,re1,im0,im1} for (k, ij) at this lane's bp
#define UENT(kk, ij) (*(const float4*)(uw + (((kk)*16 + (ij)) * 8 + bp) * 4))

  float2 o_r[8], o_i[8];
#pragma unroll
  for (int m = 0; m < 8; m++) {
    o_r[m] = make_float2(0.0f, 0.0f);
    o_i[m] = make_float2(0.0f, 0.0f);
  }

  // ---- k = 3 (g bits [1:0] = m bits [1:0]) : in-thread ----
  // o[l2*4+i] += sum_j U3[i][j] * s[l2*4+j]
#pragma unroll
  for (int i = 0; i < 4; i++) {
#pragma unroll
    for (int j = 0; j < 4; j++) {
      const float4 v = UENT(3, i * 4 + j);
      const float2 ur = make_float2(v.x, v.y), ui = make_float2(v.z, v.w);
#pragma unroll
      for (int l2 = 0; l2 < 2; l2++)
        pk_cfma(o_r[l2 * 4 + i], o_i[l2 * 4 + i], ur, ui, sr[l2 * 4 + j], si[l2 * 4 + j]);
    }
  }

  // ---- k = 2 (g bits [2:1] = m bits [2:1]) : in-thread ----
  // o[i*2+l0] += sum_j U2[i][j] * s[j*2+l0]
#pragma unroll
  for (int i = 0; i < 4; i++) {
#pragma unroll
    for (int j = 0; j < 4; j++) {
      const float4 v = UENT(2, i * 4 + j);
      const float2 ur = make_float2(v.x, v.y), ui = make_float2(v.z, v.w);
#pragma unroll
      for (int l0 = 0; l0 < 2; l0++)
        pk_cfma(o_r[i * 2 + l0], o_i[i * 2 + l0], ur, ui, sr[j * 2 + l0], si[j * 2 + l0]);
    }
  }

  // ---- k = 1 (g bits [3:2]; bit3 = q0 via lane^1, bit2 = m bit2) ----
  // o[l2*4+ll] += U1[q0*2+l2][q0*2+j2]*s[j2*4+ll] + U1[q0*2+l2][(q0^1)*2+j2]*t[j2*4+ll]
#pragma unroll
  for (int j2 = 0; j2 < 2; j2++) {
#pragma unroll
    for (int ll = 0; ll < 4; ll++) {
      const int src = j2 * 4 + ll;
      const float2 tsr = dpp2<0xB1>(sr[src]);
      const float2 tsi = dpp2<0xB1>(si[src]);
#pragma unroll
      for (int l2 = 0; l2 < 2; l2++) {
        const int i = q0 * 2 + l2;
        const int m = l2 * 4 + ll;
        const float4 vo = UENT(1, i * 4 + q0 * 2 + j2);
        pk_cfma(o_r[m], o_i[m], make_float2(vo.x, vo.y), make_float2(vo.z, vo.w),
                sr[src], si[src]);
        const float4 vp = UENT(1, i * 4 + (q0 ^ 1) * 2 + j2);
        pk_cfma(o_r[m], o_i[m], make_float2(vp.x, vp.y), make_float2(vp.z, vp.w),
                tsr, tsi);
      }
    }
  }

  // ---- k = 0 (g bits [4:3] = q) : rotations d = 0..3, U0 entry (q, q^d) ----
  {
    const float4 v0 = UENT(0, q * 4 + q);
    const float2 u0r = make_float2(v0.x, v0.y), u0i = make_float2(v0.z, v0.w);
#pragma unroll
    for (int m = 0; m < 8; m++) pk_cfma(o_r[m], o_i[m], u0r, u0i, sr[m], si[m]);

    const float4 v1 = UENT(0, q * 4 + (q ^ 1));
    const float2 u1r = make_float2(v1.x, v1.y), u1i = make_float2(v1.z, v1.w);
#pragma unroll
    for (int m = 0; m < 8; m++) {
      const float2 tr = dpp2<0xB1>(sr[m]);
      const float2 ti = dpp2<0xB1>(si[m]);
      pk_cfma(o_r[m], o_i[m], u1r, u1i, tr, ti);
    }

    const float4 v2 = UENT(0, q * 4 + (q ^ 2));
    const float2 u2r = make_float2(v2.x, v2.y), u2i = make_float2(v2.z, v2.w);
#pragma unroll
    for (int m = 0; m < 8; m++) {
      const float2 tr = dpp2<0x4E>(sr[m]);
      const float2 ti = dpp2<0x4E>(si[m]);
      pk_cfma(o_r[m], o_i[m], u2r, u2i, tr, ti);
    }

    const float4 v3 = UENT(0, q * 4 + (q ^ 3));
    const float2 u3r = make_float2(v3.x, v3.y), u3i = make_float2(v3.z, v3.w);
#pragma unroll
    for (int m = 0; m < 8; m++) {
      const float2 tr = dpp2<0x1B>(sr[m]);
      const float2 ti = dpp2<0x1B>(si[m]);
      pk_cfma(o_r[m], o_i[m], u3r, u3i, tr, ti);
    }
  }
#undef UENT

  // 16 x 8B NT stores (2 full lines per q-group per instr)
#pragma unroll
  for (int m = 0; m < 8; m++) {
    const int off = col2 + ((q * 8 + m) << 19);
    __builtin_nontemporal_store(__builtin_bit_cast(v2f, o_r[m]),
                                (v2f*)(out + off));               // real
    __builtin_nontemporal_store(__builtin_bit_cast(v2f, o_i[m]),
                                (v2f*)(out + off + (1 << 24)));   // imag
  }
}

extern "C" void kernel_launch(void* const* d_in, const int* in_sizes, int n_in,
                              void* d_out, int out_size, void* d_ws, size_t ws_size,
                              hipStream_t stream) {
  const float* Hre  = (const float*)d_in[0];
  const float* Him  = (const float*)d_in[1];
  const float* tevo = (const float*)d_in[2];
  const float* sre  = (const float*)d_in[3];
  const float* sim  = (const float*)d_in[4];
  float* out = (float*)d_out;
  float* uws = (float*)d_ws;  // UTOT floats = 8 KiB

  compute_u_kernel<<<1, 256, 0, stream>>>(Hre, Him, tevo, uws);
  apply_gates_kernel<<<NCOL / 128, 256, 0, stream>>>(sre, sim, uws, out);
}